// Round 18
// baseline (799.646 us; speedup 1.0000x reference)
//
#include <hip/hip_runtime.h>
#include <hip/hip_bf16.h>
#include <math.h>

#define SDIM 64
#define KDIM 16
#define ODIM 32
#define HDIM 30
#define TDIM 200
#define NDIM 512
#define NP 69761
#define EPSV 1e-6f
#define LOG2PIF 1.8378770664093453f

__device__ __forceinline__ float softplusf(float x) {
    return (x > 0.f) ? x + log1pf(expf(-x)) : log1pf(expf(x));
}
__device__ __forceinline__ float wave_max64(float v) {
#pragma unroll
    for (int off = 32; off; off >>= 1) v = fmaxf(v, __shfl_xor(v, off, 64));
    return v;
}
__device__ __forceinline__ float wave_sum64(float v) {
#pragma unroll
    for (int off = 32; off; off >>= 1) v += __shfl_xor(v, off, 64);
    return v;
}
__device__ __forceinline__ void bar_lds() {
    asm volatile("s_waitcnt lgkmcnt(0)\n\ts_barrier" ::: "memory");
}

// ===== TIER-1 prep: transform + B row stats + VI in ONE dispatch per n =====
__global__ __launch_bounds__(512) void prep_kernel(
    const float* __restrict__ theta, float* __restrict__ invstd,
    float* __restrict__ c0, float* __restrict__ Dws,
    float* __restrict__ pdfws, __hip_bfloat16* __restrict__ bn,
    float* __restrict__ q_ws)
{
    __shared__ float ls[SDIM * 33];          // 8448 B
    __shared__ float logC_s[SDIM], ent_s[SDIM];
    __shared__ float lse_s[1024];            // 4 KB
    __shared__ float rws_s[1024];            // 4 KB
    __shared__ float q_lds[KDIM * 68];
    __shared__ __align__(16) float v_lds[68];

    const int n = blockIdx.x, tid = threadIdx.x;
    const int wave = tid >> 6, lane = tid & 63;
    const float* thn = theta + (size_t)n * NP;

    // ---- phase 0: parameter transforms ----
    for (int idx = tid; idx < SDIM * ODIM; idx += 512) {
        float x = thn[2048 + idx];
        float sp = softplusf(x) + EPSV;
        invstd[(size_t)n * SDIM * ODIM + idx] = 1.f / sp;
        int s = idx >> 5, oo = idx & 31;
        ls[s * 33 + oo] = logf(sp);
    }
    __syncthreads();
    if (wave == 0) {
        float sum = 0.f;
#pragma unroll
        for (int oo = 0; oo < ODIM; ++oo) sum += ls[lane * 33 + oo];
        c0[n * SDIM + lane] = -sum - 16.f * LOG2PIF;
        ent_s[lane] = sum + 32.f * (0.5f + 0.5f * LOG2PIF);
    } else if (wave == 1) {
        float x = thn[69632 + lane];
        float m = wave_max64(x);
        float e = expf(x - m);
        float ssum = wave_sum64(e);
        logC_s[lane] = logf(e / ssum + EPSV);
    } else if (wave == 2) {
        float x = thn[69696 + lane];
        float m = wave_max64(x);
        float e = expf(x - m);
        float ssum = wave_sum64(e);
        Dws[n * SDIM + lane] = e / ssum;
    } else if (wave == 3) {
        float tt = thn[69760];
        float tau = 60.f / (1.f + expf(-tt)) + 1.f;
        float p = 0.f;
        if (lane < HDIM)
            p = expf((float)lane * logf(tau) - tau - lgammaf((float)lane + 1.f));
        float ssum = wave_sum64(p);
        if (lane < HDIM) pdfws[n * HDIM + lane] = p / ssum;
    }
    __syncthreads();

    // ---- phase 1: B row softmax stats + bf16 B store (wave w: rows w*128..) ----
    {
        unsigned short* bns = (unsigned short*)bn + (size_t)n * KDIM * SDIM * SDIM;
        const float lC = logC_s[lane], en = ent_s[lane];
        const float* thb = thn + 4096;
#pragma unroll 2
        for (int r = 0; r < 128; ++r) {
            const int row = wave * 128 + r;
            float x = thb[(size_t)row * 64 + lane];
            float m = wave_max64(x);
            float e = expf(x - m);
            float ssum = wave_sum64(e);
            float Bj = e / ssum;
            const int k = row >> 6, i = row & 63;
            __hip_bfloat16 h = __float2bfloat16(Bj);
            unsigned short bits;
            __builtin_memcpy(&bits, &h, 2);
            bns[(size_t)k * 4096 + (size_t)(i >> 1) * 128 + lane * 2 + (i & 1)] = bits;
            float contrib = Bj * (logf(Bj + EPSV) - lC + en);
            contrib = wave_sum64(contrib);
            if (lane == 0) {
                lse_s[row] = m + logf(ssum);
                rws_s[row] = -contrib;
            }
        }
    }
    __syncthreads();

    // ---- phase 2: VI (thread owns rows tid, tid+512), q -> q_ws ----
    {
        const float* Xn = thn + 4096;
        const float l0 = lse_s[tid], l1 = lse_s[512 + tid];
        const float rr0 = rws_s[tid], rr1 = rws_s[512 + tid];

        float4 er0[16], er1[16];
        const float* X0 = Xn + (size_t)tid * 64;
        const float* X1 = Xn + (size_t)(512 + tid) * 64;
#pragma unroll
        for (int j = 0; j < 16; ++j) {
            float4 x = *(const float4*)(X0 + j * 4);
            er0[j] = make_float4(__expf(x.x - l0), __expf(x.y - l0),
                                 __expf(x.z - l0), __expf(x.w - l0));
            float4 y = *(const float4*)(X1 + j * 4);
            er1[j] = make_float4(__expf(y.x - l1), __expf(y.y - l1),
                                 __expf(y.z - l1), __expf(y.w - l1));
        }

        float qr0 = rr0, qr1 = rr1;
        float* qw = q_ws + (size_t)n * HDIM * 1024;
        const int kq0 = tid >> 6, iq = tid & 63;
        qw[tid] = qr0;
        qw[512 + tid] = qr1;
        q_lds[kq0 * 68 + iq] = qr0;
        q_lds[(8 + kq0) * 68 + iq] = qr1;
        __syncthreads();

#pragma unroll 1
        for (int h = 1; h < HDIM; ++h) {
            if (tid < 64) {
                float m = -1e30f;
#pragma unroll
                for (int k = 0; k < KDIM; ++k) m = fmaxf(m, q_lds[k * 68 + tid]);
                float s = 0.f;
#pragma unroll
                for (int k = 0; k < KDIM; ++k) s += __expf(q_lds[k * 68 + tid] - m);
                v_lds[tid] = m + __logf(s);
            }
            bar_lds();
            float a0x = 0.f, a0y = 0.f, a0z = 0.f, a0w = 0.f;
            float a1x = 0.f, a1y = 0.f, a1z = 0.f, a1w = 0.f;
#pragma unroll
            for (int jq = 0; jq < 16; ++jq) {
                const float4 v4 = *(const float4*)&v_lds[jq * 4];
                a0x += er0[jq].x * v4.x; a0y += er0[jq].y * v4.y;
                a0z += er0[jq].z * v4.z; a0w += er0[jq].w * v4.w;
                a1x += er1[jq].x * v4.x; a1y += er1[jq].y * v4.y;
                a1z += er1[jq].z * v4.z; a1w += er1[jq].w * v4.w;
            }
            qr0 = rr0 + ((a0x + a0y) + (a0z + a0w));
            qr1 = rr1 + ((a1x + a1y) + (a1z + a1w));
            qw[(size_t)h * 1024 + tid] = qr0;
            qw[(size_t)h * 1024 + 512 + tid] = qr1;
            q_lds[kq0 * 68 + iq] = qr0;
            q_lds[(8 + kq0) * 68 + iq] = qr1;
            bar_lds();
        }
    }
}

// ======= TIER-1 fused belief+policy: 4 waves, 1 barrier/step, bf16 b policy =======
#define BSP(T_, U_) do {                                                       \
    const int cur_ = (T_) & 1, nxt_ = cur_ ^ 1;                                \
    if (wave == 3) out_b[((size_t)(T_) * NDIM + n) * SDIM + lane] = bval;      \
    if (wave == 2) {                      /* pack b_t to bf16 pairs */         \
        float eA_ = __shfl(bval, 2 * (lane & 31), 64);                         \
        float eB_ = __shfl(bval, 2 * (lane & 31) + 1, 64);                     \
        if (lane < 32) {                                                       \
            __hip_bfloat16 hA_ = __float2bfloat16(eA_);                        \
            __hip_bfloat16 hB_ = __float2bfloat16(eB_);                        \
            unsigned short ba_, bb_;                                           \
            __builtin_memcpy(&ba_, &hA_, 2);                                   \
            __builtin_memcpy(&bb_, &hB_, 2);                                   \
            b2u_s[cur_][lane] = (uint)ba_ | ((uint)bb_ << 16);                 \
        }                                                                      \
    }                                                                          \
    {   /* belief matvec via shfl-distributed b */                             \
        float a0_ = 0.f, a1_ = 0.f, a2_ = 0.f, a3_ = 0.f;                      \
        _Pragma("unroll")                                                      \
        for (int j_ = 0; j_ < 4; ++j_) {                                       \
            a0_ += er[4 * j_ + 0] * __shfl(bval, rbase + 4 * j_ + 0, 64);      \
            a1_ += er[4 * j_ + 1] * __shfl(bval, rbase + 4 * j_ + 1, 64);      \
            a2_ += er[4 * j_ + 2] * __shfl(bval, rbase + 4 * j_ + 2, 64);      \
            a3_ += er[4 * j_ + 3] * __shfl(bval, rbase + 4 * j_ + 3, 64);      \
        }                                                                      \
        part_s[cur_][wave][lane] = (a0_ + a1_) + (a2_ + a3_);                  \
    }                                                                          \
    if ((T_) + 1 < TDIM) {               /* z2 partial for t+1 */              \
        const float* om_ = &o_s[((T_) + 1) * ODIM + ob];                       \
        float zz_ = 0.f;                                                       \
        _Pragma("unroll")                                                      \
        for (int j_ = 0; j_ < 8; ++j_) {                                       \
            float z_ = (om_[j_] - mean_r[j_]) * istd_r[j_];                    \
            zz_ += z_ * z_;                                                    \
        }                                                                      \
        z2p_s[nxt_][wave][lane] = zz_;                                         \
    }                                                                          \
    _Pragma("unroll")                     /* unpack next-step B rows */        \
    for (int m_ = 0; m_ < 8; ++m_) {                                           \
        er[2 * m_]     = __uint_as_float(U_[m_] << 16);                        \
        er[2 * m_ + 1] = __uint_as_float(U_[m_] & 0xffff0000u);                \
    }                                                                          \
    {   /* prefetch B(a_{T+3}) */                                              \
        const int tl_ = ((T_) + 3 < TDIM) ? (T_) + 3 : TDIM - 1;               \
        const uint* up_ = bnn32 + (size_t)a_s[tl_] * 2048 + (rbase >> 1) * 64 + lane; \
        _Pragma("unroll")                                                      \
        for (int m_ = 0; m_ < 8; ++m_) U_[m_] = up_[m_ * 64];                  \
    }                                                                          \
    bar_lds();                           /* the ONE barrier */                 \
    {   /* belief update (x4 redundant) + pipelined ecz(t+1) */                \
        float sv_ = part_s[cur_][0][lane] + part_s[cur_][1][lane]              \
                  + part_s[cur_][2][lane] + part_s[cur_][3][lane];             \
        float u_ = (sv_ + EPSV) * ecz_cur;                                     \
        float S_ = wave_sum64(u_);                                             \
        if (wave == 0 && lane == 0)                                            \
            out_lp[(size_t)(T_) * NDIM + n] = cm_cur + __logf(S_);             \
        bval = u_ / S_;                                                        \
        float z2n_ = z2p_s[nxt_][0][lane] + z2p_s[nxt_][1][lane]               \
                   + z2p_s[nxt_][2][lane] + z2p_s[nxt_][3][lane];              \
        float cn_ = c0_r - 0.5f * z2n_;                                        \
        cm_cur = wave_max64(cn_);                                              \
        ecz_cur = __expf(cn_ - cm_cur);                                        \
    }                                                                          \
    {   /* policy(T) from bf16 b2u_s[cur_] (written pre-barrier) */            \
        const uint4* bp_ = (const uint4*)&b2u_s[cur_][0];                      \
        float aAx_ = 0.f, aAy_ = 0.f, aAz_ = 0.f, aAw_ = 0.f;                  \
        float aBx_ = 0.f, aBy_ = 0.f, aBz_ = 0.f, aBw_ = 0.f;                  \
        _Pragma("unroll")                                                      \
        for (int r_ = 0; r_ < 8; ++r_) {                                       \
            const uint4 u_ = bp_[r_];                                          \
            const float b0_ = __uint_as_float(u_.x << 16);                     \
            const float b1_ = __uint_as_float(u_.x & 0xffff0000u);             \
            const float b2_ = __uint_as_float(u_.y << 16);                     \
            const float b3_ = __uint_as_float(u_.y & 0xffff0000u);             \
            const float b4_ = __uint_as_float(u_.z << 16);                     \
            const float b5_ = __uint_as_float(u_.z & 0xffff0000u);             \
            const float b6_ = __uint_as_float(u_.w << 16);                     \
            const float b7_ = __uint_as_float(u_.w & 0xffff0000u);             \
            const float4 qa0_ = qA[2 * r_], qb0_ = qA[2 * r_ + 1];             \
            const float4 qa1_ = qB[2 * r_], qb1_ = qB[2 * r_ + 1];             \
            aAx_ += qa0_.x * b0_; aAy_ += qa0_.y * b1_;                        \
            aAz_ += qa0_.z * b2_; aAw_ += qa0_.w * b3_;                        \
            aAx_ += qb0_.x * b4_; aAy_ += qb0_.y * b5_;                        \
            aAz_ += qb0_.z * b6_; aAw_ += qb0_.w * b7_;                        \
            aBx_ += qa1_.x * b0_; aBy_ += qa1_.y * b1_;                        \
            aBz_ += qa1_.z * b2_; aBw_ += qa1_.w * b3_;                        \
            aBx_ += qb1_.x * b4_; aBy_ += qb1_.y * b5_;                        \
            aBz_ += qb1_.z * b6_; aBw_ += qb1_.w * b7_;                        \
        }                                                                      \
        float aA_ = (aAx_ + aAy_) + (aAz_ + aAw_);                             \
        float aB_ = (aBx_ + aBy_) + (aBz_ + aBw_);                             \
        float mA_ = aA_, mB_ = aB_;                                            \
        mA_ = fmaxf(mA_, __shfl_xor(mA_, 1, 64));                              \
        mB_ = fmaxf(mB_, __shfl_xor(mB_, 1, 64));                              \
        mA_ = fmaxf(mA_, __shfl_xor(mA_, 2, 64));                              \
        mB_ = fmaxf(mB_, __shfl_xor(mB_, 2, 64));                              \
        mA_ = fmaxf(mA_, __shfl_xor(mA_, 4, 64));                              \
        mB_ = fmaxf(mB_, __shfl_xor(mB_, 4, 64));                              \
        mA_ = fmaxf(mA_, __shfl_xor(mA_, 8, 64));                              \
        mB_ = fmaxf(mB_, __shfl_xor(mB_, 8, 64));                              \
        float eA_ = __expf(aA_ - mA_), eB_ = __expf(aB_ - mB_);                \
        float SA_ = eA_, SB_ = eB_;                                            \
        SA_ += __shfl_xor(SA_, 1, 64);  SB_ += __shfl_xor(SB_, 1, 64);         \
        SA_ += __shfl_xor(SA_, 2, 64);  SB_ += __shfl_xor(SB_, 2, 64);         \
        SA_ += __shfl_xor(SA_, 4, 64);  SB_ += __shfl_xor(SB_, 4, 64);         \
        SA_ += __shfl_xor(SA_, 8, 64);  SB_ += __shfl_xor(SB_, 8, 64);         \
        float val_ = pdfA * eA_ / SA_ + pdfB * eB_ / SB_;                      \
        val_ += __shfl_xor(val_, 16, 64);                                      \
        val_ += __shfl_xor(val_, 32, 64);                                      \
        if (lane < 16) p2_s[cur_][wave][lane] = val_;                          \
        if ((T_) > 0 && wave == 3 && lane < 16) {                              \
            float s4_ = p2_s[nxt_][0][lane] + p2_s[nxt_][1][lane]              \
                      + p2_s[nxt_][2][lane] + p2_s[nxt_][3][lane];             \
            out_pi[((size_t)((T_) - 1) * NDIM + n) * KDIM + lane] = s4_;       \
        }                                                                      \
    }                                                                          \
} while (0)

__global__ __launch_bounds__(256, 2) void bp_kernel(
    const float* __restrict__ o, const int* __restrict__ a,
    const float* __restrict__ theta, const __hip_bfloat16* __restrict__ bn,
    const float* __restrict__ invstd, const float* __restrict__ c0g,
    const float* __restrict__ Dws, const float* __restrict__ pdfg,
    const float* __restrict__ q_ws,
    float* __restrict__ out_pi, float* __restrict__ out_b,
    float* __restrict__ out_lp)
{
    __shared__ float o_s[TDIM * ODIM];       // 25.6 KB
    __shared__ int   a_s[TDIM];
    __shared__ float mean_s[SDIM * 33];
    __shared__ float istd_s[SDIM * 33];
    __shared__ float c0_sh[SDIM];
    __shared__ float part_s[2][4][68];
    __shared__ float z2p_s[2][4][SDIM];
    __shared__ __align__(16) uint b2u_s[2][32];
    __shared__ float p2_s[2][4][17];

    const int n = blockIdx.x, tid = threadIdx.x;
    const int wave = tid >> 6, lane = tid & 63;
    const int rbase = wave * 16, ob = wave * 8;
    const float* thn = theta + (size_t)n * NP;
    const uint* bnn32 = (const uint*)(bn + (size_t)n * KDIM * SDIM * SDIM);

    for (int idx = tid; idx < TDIM * ODIM; idx += 256)
        o_s[idx] = o[((size_t)(idx >> 5) * NDIM + n) * ODIM + (idx & 31)];
    if (tid < TDIM) a_s[tid] = a[tid * NDIM + n];
    for (int idx = tid; idx < SDIM * ODIM; idx += 256) {
        int s = idx >> 5, oo = idx & 31;
        mean_s[s * 33 + oo] = thn[idx];
        istd_s[s * 33 + oo] = invstd[(size_t)n * SDIM * ODIM + idx];
    }
    if (tid < SDIM) c0_sh[tid] = c0g[n * SDIM + tid];

    // --- policy state: q-rows in registers ---
    const int hA = tid >> 4, kA = tid & 15, hB = hA + 16;
    const float* qnp = q_ws + (size_t)n * HDIM * 1024;
    float4 qA[16], qB[16];
#pragma unroll
    for (int jq = 0; jq < 16; ++jq)
        qA[jq] = *(const float4*)&qnp[(size_t)hA * 1024 + kA * 64 + jq * 4];
    if (hB < HDIM) {
#pragma unroll
        for (int jq = 0; jq < 16; ++jq)
            qB[jq] = *(const float4*)&qnp[(size_t)hB * 1024 + kA * 64 + jq * 4];
    } else {
#pragma unroll
        for (int jq = 0; jq < 16; ++jq) qB[jq] = make_float4(0.f, 0.f, 0.f, 0.f);
    }
    const float pdfA = pdfg[n * HDIM + hA];
    const float pdfB = (hB < HDIM) ? pdfg[n * HDIM + hB] : 0.f;
    __syncthreads();

    const float c0_r = c0_sh[lane];
    float bval = Dws[n * SDIM + lane];
    float mean_r[8], istd_r[8];
#pragma unroll
    for (int j = 0; j < 8; ++j) {
        mean_r[j] = mean_s[lane * 33 + ob + j];
        istd_r[j] = istd_s[lane * 33 + ob + j];
    }

    float er[16];
    uint u0[8], u1[8];
    {   // prologue: er <- B(a_0); u0 <- B(a_1); u1 <- B(a_2)
        const uint* p0 = bnn32 + (size_t)a_s[0] * 2048 + (rbase >> 1) * 64 + lane;
#pragma unroll
        for (int m = 0; m < 8; ++m) u0[m] = p0[m * 64];
#pragma unroll
        for (int m = 0; m < 8; ++m) {
            er[2 * m]     = __uint_as_float(u0[m] << 16);
            er[2 * m + 1] = __uint_as_float(u0[m] & 0xffff0000u);
        }
        const uint* p1 = bnn32 + (size_t)a_s[1] * 2048 + (rbase >> 1) * 64 + lane;
#pragma unroll
        for (int m = 0; m < 8; ++m) u0[m] = p1[m * 64];
        const uint* p2 = bnn32 + (size_t)a_s[2] * 2048 + (rbase >> 1) * 64 + lane;
#pragma unroll
        for (int m = 0; m < 8; ++m) u1[m] = p2[m * 64];
    }
    {   // z2p for t=0
        const float* om = &o_s[ob];
        float zz = 0.f;
#pragma unroll
        for (int j = 0; j < 8; ++j) {
            float z = (om[j] - mean_r[j]) * istd_r[j];
            zz += z * z;
        }
        z2p_s[0][wave][lane] = zz;
    }
    __syncthreads();
    float ecz_cur, cm_cur;
    {   // ecz(0)
        float z2 = z2p_s[0][0][lane] + z2p_s[0][1][lane]
                 + z2p_s[0][2][lane] + z2p_s[0][3][lane];
        float c = c0_r - 0.5f * z2;
        cm_cur = wave_max64(c);
        ecz_cur = __expf(c - cm_cur);
    }

#pragma unroll 1
    for (int t = 0; t < TDIM; t += 2) {
        BSP(t, u0);
        BSP(t + 1, u1);
    }
    __syncthreads();
    if (wave == 3 && lane < 16) {    // emit pi(TDIM-1), buffer (TDIM-1)&1 = 1
        float s4 = p2_s[1][0][lane] + p2_s[1][1][lane]
                 + p2_s[1][2][lane] + p2_s[1][3][lane];
        out_pi[((size_t)(TDIM - 1) * NDIM + n) * KDIM + lane] = s4;
    }
}

// ===================== TIER-3 fallback kernels (no extra ws) =====================
__global__ __launch_bounds__(256) void transform_kernel(
    const float* __restrict__ theta, float* __restrict__ invstd,
    float* __restrict__ c0, float* __restrict__ ent,
    float* __restrict__ logC, float* __restrict__ Dws,
    float* __restrict__ pdfws)
{
    __shared__ float ls[SDIM * 33];
    const int n = blockIdx.x, tid = threadIdx.x;
    const float* thn = theta + (size_t)n * NP;

    for (int idx = tid; idx < SDIM * ODIM; idx += 256) {
        float x = thn[2048 + idx];
        float sp = softplusf(x) + EPSV;
        invstd[(size_t)n * SDIM * ODIM + idx] = 1.f / sp;
        int s = idx >> 5, oo = idx & 31;
        ls[s * 33 + oo] = logf(sp);
    }
    __syncthreads();

    const int wave = tid >> 6, lane = tid & 63;
    if (wave == 0) {
        float sum = 0.f;
#pragma unroll
        for (int oo = 0; oo < ODIM; ++oo) sum += ls[lane * 33 + oo];
        c0[n * SDIM + lane]  = -sum - 16.f * LOG2PIF;
        ent[n * SDIM + lane] =  sum + 32.f * (0.5f + 0.5f * LOG2PIF);
    } else if (wave == 1) {
        float x = thn[69632 + lane];
        float m = wave_max64(x);
        float e = expf(x - m);
        float ssum = wave_sum64(e);
        logC[n * SDIM + lane] = logf(e / ssum + EPSV);
    } else if (wave == 2) {
        float x = thn[69696 + lane];
        float m = wave_max64(x);
        float e = expf(x - m);
        float ssum = wave_sum64(e);
        Dws[n * SDIM + lane] = e / ssum;
    } else {
        float tt = thn[69760];
        float tau = 60.f / (1.f + expf(-tt)) + 1.f;
        float p = 0.f;
        if (lane < HDIM)
            p = expf((float)lane * logf(tau) - tau - lgammaf((float)lane + 1.f));
        float ssum = wave_sum64(p);
        if (lane < HDIM) pdfws[n * HDIM + lane] = p / ssum;
    }
}

__global__ __launch_bounds__(256) void row_stats_kernel(
    const float* __restrict__ theta, const float* __restrict__ logC,
    const float* __restrict__ ent, float* __restrict__ lse,
    float* __restrict__ rws)
{
    const int lane = threadIdx.x & 63;
    const int base_row = (blockIdx.x * 4 + (threadIdx.x >> 6)) * 16;
    const int n = base_row >> 10;
    const float lC = logC[n * SDIM + lane];
    const float en = ent[n * SDIM + lane];
    const float* thb = theta + (size_t)n * NP + 4096;

#pragma unroll 1
    for (int r = 0; r < 16; ++r) {
        const int row = base_row + r;
        const int rl = row & 1023;
        float x = thb[(size_t)rl * 64 + lane];
        float m = wave_max64(x);
        float e = expf(x - m);
        float ssum = wave_sum64(e);
        float Bj = e / ssum;
        float contrib = Bj * (logf(Bj + EPSV) - lC + en);
        contrib = wave_sum64(contrib);
        if (lane == 0) {
            lse[row] = m + logf(ssum);
            rws[row] = -contrib;
        }
    }
}

#define Z2PART(TT_, BUF_) do {                                                 \
    const int ob_ = (wave - 1) * 8;                                            \
    const float* om_ = &o_s[(TT_) * ODIM + ob_];                               \
    float zz_ = 0.f;                                                           \
    _Pragma("unroll")                                                          \
    for (int j_ = 0; j_ < 8; ++j_) {                                           \
        float z_ = (om_[j_] - mean_s[lane * 33 + ob_ + j_])                    \
                 * istd_s[lane * 33 + ob_ + j_];                               \
        zz_ += z_ * z_;                                                        \
    }                                                                          \
    z2p_s[BUF_][wave - 1][lane] = zz_;                                         \
} while (0)

#define BSTEP(T_, RAW_) do {                                                   \
    const int cur_ = (T_) & 1, nxt_ = cur_ ^ 1;                                \
    if (wave >= 1) {                                                           \
        float acc_ = 0.f;                                                      \
        _Pragma("unroll")                                                      \
        for (int ii = 0; ii < 10; ++ii)                                        \
            if (ii < nrow) acc_ += er[ii] * b_s[cur_][rbase + ii];             \
        part_s[wave - 1][lane] = acc_;                                         \
        if (wave == 6) out_b[((size_t)(T_) * NDIM + n) * SDIM + lane] = b_s[cur_][lane]; \
    }                                                                          \
    bar_lds();                                                                 \
    if (wave == 0) {                                                           \
        float sv_ = part_s[0][lane] + part_s[1][lane] + part_s[2][lane]        \
                  + part_s[3][lane] + part_s[4][lane] + part_s[5][lane]        \
                  + part_s[6][lane];                                           \
        float z2_ = z2p_s[cur_][0][lane] + z2p_s[cur_][1][lane]                \
                  + z2p_s[cur_][2][lane] + z2p_s[cur_][3][lane];               \
        float joint_ = __logf(sv_ + EPSV) + c0_s[lane] - 0.5f * z2_;           \
        float m_ = wave_max64(joint_);                                         \
        float e_ = __expf(joint_ - m_);                                        \
        float ss_ = wave_sum64(e_);                                            \
        b_s[nxt_][lane] = e_ / ss_;                                            \
        if (lane == 0) out_lp[(size_t)(T_) * NDIM + n] = m_ + __logf(ss_);     \
    } else {                                                                   \
        if ((T_) + 1 < TDIM) {                                                 \
            const int an_ = a_s[(T_) + 1];                                     \
            const float* ln_ = lseA + an_ * SDIM;                              \
            _Pragma("unroll")                                                  \
            for (int ii = 0; ii < 10; ++ii)                                    \
                if (ii < nrow) er[ii] = __expf(RAW_[ii] - ln_[rbase + ii]);    \
            if (wave <= 4) Z2PART((T_) + 1, nxt_);                             \
        }                                                                      \
        const int tl_ = ((T_) + 3 < TDIM) ? (T_) + 3 : TDIM - 1;               \
        const int a3_ = a_s[tl_];                                              \
        const float* X3_ = Xn + (size_t)a3_ * SDIM * SDIM;                     \
        _Pragma("unroll")                                                      \
        for (int ii = 0; ii < 10; ++ii)                                        \
            if (ii < nrow) RAW_[ii] = X3_[(size_t)(rbase + ii) * SDIM + lane]; \
    }                                                                          \
    bar_lds();                                                                 \
} while (0)

__global__ __launch_bounds__(512) void belief_kernel(
    const float* __restrict__ o, const int* __restrict__ a,
    const float* __restrict__ theta, const float* __restrict__ lse,
    const float* __restrict__ invstd, const float* __restrict__ c0g,
    const float* __restrict__ Dws,
    float* __restrict__ out_b, float* __restrict__ out_lp)
{
    __shared__ float o_s[TDIM * ODIM];
    __shared__ int   a_s[TDIM];
    __shared__ float mean_s[SDIM * 33];
    __shared__ float istd_s[SDIM * 33];
    __shared__ float lseA[KDIM * SDIM];
    __shared__ float c0_s[SDIM];
    __shared__ float b_s[2][SDIM];
    __shared__ float part_s[7][68];
    __shared__ float z2p_s[2][4][SDIM];

    const int n = blockIdx.x, tid = threadIdx.x;
    const int wave = tid >> 6, lane = tid & 63;
    const float* thn = theta + (size_t)n * NP;
    const float* Xn  = thn + 4096;

    for (int idx = tid; idx < TDIM * ODIM; idx += 512)
        o_s[idx] = o[((size_t)(idx >> 5) * NDIM + n) * ODIM + (idx & 31)];
    if (tid < TDIM) a_s[tid] = a[tid * NDIM + n];
    for (int idx = tid; idx < SDIM * ODIM; idx += 512) {
        int s = idx >> 5, oo = idx & 31;
        mean_s[s * 33 + oo] = thn[idx];
        istd_s[s * 33 + oo] = invstd[(size_t)n * SDIM * ODIM + idx];
    }
    for (int idx = tid; idx < KDIM * SDIM; idx += 512)
        lseA[idx] = lse[(size_t)n * KDIM * SDIM + idx];
    if (tid < SDIM) { c0_s[tid] = c0g[n * SDIM + tid]; b_s[0][tid] = Dws[n * SDIM + tid]; }
    __syncthreads();

    const int rbase = (wave >= 1) ? (wave - 1) * 10 : 0;
    const int nrow  = (wave >= 1) ? ((SDIM - rbase) < 10 ? (SDIM - rbase) : 10) : 0;

    float er[10], raw0[10], raw1[10];
    if (wave >= 1) {
        const int a0 = a_s[0];
        const float* X0 = Xn + (size_t)a0 * SDIM * SDIM;
        const float* l0 = lseA + a0 * SDIM;
#pragma unroll
        for (int ii = 0; ii < 10; ++ii)
            if (ii < nrow) er[ii] = __expf(X0[(size_t)(rbase + ii) * SDIM + lane] - l0[rbase + ii]);
        const int a1 = a_s[1];
        const float* X1 = Xn + (size_t)a1 * SDIM * SDIM;
#pragma unroll
        for (int ii = 0; ii < 10; ++ii)
            if (ii < nrow) raw0[ii] = X1[(size_t)(rbase + ii) * SDIM + lane];
        const int a2 = a_s[2];
        const float* X2 = Xn + (size_t)a2 * SDIM * SDIM;
#pragma unroll
        for (int ii = 0; ii < 10; ++ii)
            if (ii < nrow) raw1[ii] = X2[(size_t)(rbase + ii) * SDIM + lane];
        if (wave <= 4) Z2PART(0, 0);
    }
    __syncthreads();

#pragma unroll 1
    for (int t = 0; t < TDIM; t += 2) {
        BSTEP(t, raw0);
        BSTEP(t + 1, raw1);
    }
}

__global__ __launch_bounds__(512) void vi_policy_kernel(
    const float* __restrict__ theta, const float* __restrict__ lse,
    const float* __restrict__ rws, const float* __restrict__ pdfg,
    const float* __restrict__ out_b_g, float* __restrict__ out_pi)
{
    __shared__ __align__(16) float q_s[HDIM * KDIM * 68];
    __shared__ float r_s[KDIM * SDIM];
    __shared__ float lse_s[KDIM * SDIM];
    __shared__ __align__(16) float v_s[SDIM];
    __shared__ __align__(16) float b_lds[64 * 68];
    __shared__ float pdf_s[32];

    const int n = blockIdx.x, tid = threadIdx.x;
    const int wave = tid >> 6, lane = tid & 63;
    const int sub = lane & 15, rq = lane >> 4;
    const float* Xn = theta + (size_t)n * NP + 4096;

    for (int idx = tid; idx < KDIM * SDIM; idx += 512) {
        r_s[idx]   = rws[(size_t)n * KDIM * SDIM + idx];
        lse_s[idx] = lse[(size_t)n * KDIM * SDIM + idx];
    }
    if (tid < HDIM) pdf_s[tid] = pdfg[n * HDIM + tid];
    __syncthreads();

    for (int idx = tid; idx < KDIM * SDIM; idx += 512)
        q_s[(idx >> 6) * 68 + (idx & 63)] = r_s[idx];

    float4 breg[32];
#pragma unroll
    for (int it = 0; it < 32; ++it) {
        const int row = it * 32 + wave * 4 + rq;
        const float* xr = Xn + (size_t)row * SDIM + sub * 4;
        const float l = lse_s[row];
        breg[it] = make_float4(__expf(xr[0] - l), __expf(xr[1] - l),
                               __expf(xr[2] - l), __expf(xr[3] - l));
    }
    bar_lds();

#pragma unroll 1
    for (int h = 1; h < HDIM; ++h) {
        if (tid < SDIM) {
            const int base = (h - 1) * KDIM;
            float m = -1e30f;
#pragma unroll
            for (int k = 0; k < KDIM; ++k) m = fmaxf(m, q_s[(base + k) * 68 + tid]);
            float ssum = 0.f;
#pragma unroll
            for (int k = 0; k < KDIM; ++k) ssum += __expf(q_s[(base + k) * 68 + tid] - m);
            v_s[tid] = m + __logf(ssum);
        }
        bar_lds();
        const float4 v4 = *(const float4*)&v_s[sub * 4];
#pragma unroll
        for (int it = 0; it < 32; ++it) {
            const int row = it * 32 + wave * 4 + rq;
            float acc = breg[it].x * v4.x + breg[it].y * v4.y
                      + breg[it].z * v4.z + breg[it].w * v4.w;
            acc += __shfl_xor(acc, 1, 64);
            acc += __shfl_xor(acc, 2, 64);
            acc += __shfl_xor(acc, 4, 64);
            acc += __shfl_xor(acc, 8, 64);
            if (sub == 0)
                q_s[(h * KDIM + (row >> 6)) * 68 + (row & 63)] = r_s[row] + acc;
        }
        bar_lds();
    }

    const int tc = tid >> 4, kk = tid & 15;
#pragma unroll 1
    for (int t0 = 0; t0 < TDIM; t0 += 64) {
        const int nt = (TDIM - t0) < 64 ? (TDIM - t0) : 64;
        for (int idx = tid; idx < nt * 16; idx += 512) {
            const int row = idx >> 4, jq = idx & 15;
            *(float4*)&b_lds[row * 68 + jq * 4] =
                *(const float4*)&out_b_g[(((size_t)(t0 + row)) * NDIM + n) * SDIM + jq * 4];
        }
        bar_lds();
        const bool vA = tc < nt, vB = (tc + 32) < nt;
        float4 bqA[16], bqB[16];
        if (vA) {
#pragma unroll
            for (int jq = 0; jq < 16; ++jq)
                bqA[jq] = *(const float4*)&b_lds[tc * 68 + jq * 4];
        }
        if (vB) {
#pragma unroll
            for (int jq = 0; jq < 16; ++jq)
                bqB[jq] = *(const float4*)&b_lds[(tc + 32) * 68 + jq * 4];
        }
        float pikA = 0.f, pikB = 0.f;
#pragma unroll 1
        for (int h = 0; h < HDIM; ++h) {
            const float* qr = &q_s[(h * KDIM + kk) * 68];
            float aA = 0.f, aB = 0.f;
#pragma unroll
            for (int jq = 0; jq < 16; ++jq) {
                const float4 qv = *(const float4*)&qr[jq * 4];
                if (vA) aA += qv.x * bqA[jq].x + qv.y * bqA[jq].y
                            + qv.z * bqA[jq].z + qv.w * bqA[jq].w;
                if (vB) aB += qv.x * bqB[jq].x + qv.y * bqB[jq].y
                            + qv.z * bqB[jq].z + qv.w * bqB[jq].w;
            }
            float mA = aA, mB = aB;
            mA = fmaxf(mA, __shfl_xor(mA, 1, 64));
            mA = fmaxf(mA, __shfl_xor(mA, 2, 64));
            mA = fmaxf(mA, __shfl_xor(mA, 4, 64));
            mA = fmaxf(mA, __shfl_xor(mA, 8, 64));
            mB = fmaxf(mB, __shfl_xor(mB, 1, 64));
            mB = fmaxf(mB, __shfl_xor(mB, 2, 64));
            mB = fmaxf(mB, __shfl_xor(mB, 4, 64));
            mB = fmaxf(mB, __shfl_xor(mB, 8, 64));
            float eA = __expf(aA - mA), eB = __expf(aB - mB);
            float SA = eA, SB = eB;
            SA += __shfl_xor(SA, 1, 64);
            SA += __shfl_xor(SA, 2, 64);
            SA += __shfl_xor(SA, 4, 64);
            SA += __shfl_xor(SA, 8, 64);
            SB += __shfl_xor(SB, 1, 64);
            SB += __shfl_xor(SB, 2, 64);
            SB += __shfl_xor(SB, 4, 64);
            SB += __shfl_xor(SB, 8, 64);
            const float ph = pdf_s[h];
            pikA += ph * eA / SA;
            pikB += ph * eB / SB;
        }
        if (vA) out_pi[(((size_t)(t0 + tc)) * NDIM + n) * KDIM + kk] = pikA;
        if (vB) out_pi[(((size_t)(t0 + 32 + tc)) * NDIM + n) * KDIM + kk] = pikB;
        bar_lds();
    }
}

extern "C" void kernel_launch(void* const* d_in, const int* in_sizes, int n_in,
                              void* d_out, int out_size, void* d_ws, size_t ws_size,
                              hipStream_t stream) {
    (void)in_sizes; (void)n_in; (void)out_size;
    const float* o     = (const float*)d_in[0];
    const int*   a     = (const int*)d_in[1];
    const float* theta = (const float*)d_in[2];
    float* out = (float*)d_out;
    float* ws  = (float*)d_ws;

    float* lse    = ws;                                   // N*K*S
    float* rws    = lse    + (size_t)NDIM * KDIM * SDIM;  // N*K*S
    float* invstd = rws    + (size_t)NDIM * KDIM * SDIM;  // N*S*O
    float* c0     = invstd + (size_t)NDIM * SDIM * ODIM;  // N*S
    float* ent    = c0     + (size_t)NDIM * SDIM;         // N*S
    float* logC   = ent    + (size_t)NDIM * SDIM;         // N*S
    float* Dws    = logC   + (size_t)NDIM * SDIM;         // N*S
    float* pdfws  = Dws    + (size_t)NDIM * SDIM;         // N*H
    float* q_ws   = pdfws  + (size_t)NDIM * HDIM;         // N*H*K*S f32 (63 MB)
    __hip_bfloat16* bn = (__hip_bfloat16*)(q_ws + (size_t)NDIM * HDIM * KDIM * SDIM);

    const size_t f_base = (size_t)NDIM * KDIM * SDIM * 2
                        + (size_t)NDIM * SDIM * ODIM
                        + (size_t)NDIM * SDIM * 4
                        + (size_t)NDIM * HDIM;
    const size_t f_q  = (size_t)NDIM * HDIM * KDIM * SDIM;
    const size_t need1 = (f_base + f_q) * 4
                       + (size_t)NDIM * KDIM * SDIM * SDIM * 2;   // ~139 MB

    float* out_pi = out;
    float* out_b  = out + (size_t)TDIM * NDIM * KDIM;
    float* out_lp = out + (size_t)TDIM * NDIM * KDIM + (size_t)TDIM * NDIM * SDIM;

    if (ws_size >= need1) {
        prep_kernel<<<NDIM, 512, 0, stream>>>(theta, invstd, c0, Dws, pdfws, bn, q_ws);
        bp_kernel<<<NDIM, 256, 0, stream>>>(
            o, a, theta, bn, invstd, c0, Dws, pdfws, q_ws, out_pi, out_b, out_lp);
    } else {
        transform_kernel<<<NDIM, 256, 0, stream>>>(theta, invstd, c0, ent, logC, Dws, pdfws);
        row_stats_kernel<<<8192, 256, 0, stream>>>(theta, logC, ent, lse, rws);
        belief_kernel<<<NDIM, 512, 0, stream>>>(
            o, a, theta, lse, invstd, c0, Dws, out_b, out_lp);
        vi_policy_kernel<<<NDIM, 512, 0, stream>>>(theta, lse, rws, pdfws, out_b, out_pi);
    }
}

// Round 19
// 589.251 us; speedup vs baseline: 1.3571x; 1.3571x over previous
//
#include <hip/hip_runtime.h>
#include <hip/hip_bf16.h>
#include <math.h>

#define SDIM 64
#define KDIM 16
#define ODIM 32
#define HDIM 30
#define TDIM 200
#define NDIM 512
#define NP 69761
#define EPSV 1e-6f
#define LOG2PIF 1.8378770664093453f

__device__ __forceinline__ float softplusf(float x) {
    return (x > 0.f) ? x + log1pf(expf(-x)) : log1pf(expf(x));
}
__device__ __forceinline__ float wave_max64(float v) {
#pragma unroll
    for (int off = 32; off; off >>= 1) v = fmaxf(v, __shfl_xor(v, off, 64));
    return v;
}
__device__ __forceinline__ float wave_sum64(float v) {
#pragma unroll
    for (int off = 32; off; off >>= 1) v += __shfl_xor(v, off, 64);
    return v;
}
__device__ __forceinline__ void bar_lds() {
    asm volatile("s_waitcnt lgkmcnt(0)\n\ts_barrier" ::: "memory");
}

// ---------------- kernel 1: per-n parameter transforms ----------------
__global__ __launch_bounds__(256) void transform_kernel(
    const float* __restrict__ theta, float* __restrict__ invstd,
    float* __restrict__ c0, float* __restrict__ ent,
    float* __restrict__ logC, float* __restrict__ Dws,
    float* __restrict__ pdfws)
{
    __shared__ float ls[SDIM * 33];
    const int n = blockIdx.x, tid = threadIdx.x;
    const float* thn = theta + (size_t)n * NP;

    for (int idx = tid; idx < SDIM * ODIM; idx += 256) {
        float x = thn[2048 + idx];
        float sp = softplusf(x) + EPSV;            // A_std
        invstd[(size_t)n * SDIM * ODIM + idx] = 1.f / sp;
        int s = idx >> 5, oo = idx & 31;
        ls[s * 33 + oo] = logf(sp);
    }
    __syncthreads();

    const int wave = tid >> 6, lane = tid & 63;
    if (wave == 0) {
        float sum = 0.f;
#pragma unroll
        for (int oo = 0; oo < ODIM; ++oo) sum += ls[lane * 33 + oo];
        c0[n * SDIM + lane]  = -sum - 16.f * LOG2PIF;
        ent[n * SDIM + lane] =  sum + 32.f * (0.5f + 0.5f * LOG2PIF);
    } else if (wave == 1) {
        float x = thn[69632 + lane];
        float m = wave_max64(x);
        float e = expf(x - m);
        float ssum = wave_sum64(e);
        logC[n * SDIM + lane] = logf(e / ssum + EPSV);
    } else if (wave == 2) {
        float x = thn[69696 + lane];
        float m = wave_max64(x);
        float e = expf(x - m);
        float ssum = wave_sum64(e);
        Dws[n * SDIM + lane] = e / ssum;
    } else {
        float tt = thn[69760];
        float tau = 60.f / (1.f + expf(-tt)) + 1.f;
        float p = 0.f;
        if (lane < HDIM)
            p = expf((float)lane * logf(tau) - tau - lgammaf((float)lane + 1.f));
        float ssum = wave_sum64(p);
        if (lane < HDIM) pdfws[n * HDIM + lane] = p / ssum;
    }
}

// ---- kernel 2: B row stats, 16 rows per wave (grid 8192, low block overhead) ----
__global__ __launch_bounds__(256) void row_stats_kernel(
    const float* __restrict__ theta, const float* __restrict__ logC,
    const float* __restrict__ ent, float* __restrict__ lse,
    float* __restrict__ rws, __hip_bfloat16* __restrict__ bn)
{
    const int lane = threadIdx.x & 63;
    const int base_row = (blockIdx.x * 4 + (threadIdx.x >> 6)) * 16;
    const int n = base_row >> 10;                    // constant within block
    const float lC = logC[n * SDIM + lane];
    const float en = ent[n * SDIM + lane];
    const float* thb = theta + (size_t)n * NP + 4096;
    unsigned short* bns = bn ? (unsigned short*)bn + (size_t)n * KDIM * SDIM * SDIM : nullptr;

#pragma unroll 1
    for (int r = 0; r < 16; ++r) {
        const int row = base_row + r;
        const int rl = row & 1023;
        float x = thb[(size_t)rl * 64 + lane];
        float m = wave_max64(x);
        float e = expf(x - m);
        float ssum = wave_sum64(e);
        float Bj = e / ssum;
        if (bns) {
            const int k = rl >> 6, i = rl & 63;
            __hip_bfloat16 h = __float2bfloat16(Bj);
            unsigned short bits;
            __builtin_memcpy(&bits, &h, 2);
            bns[(size_t)k * 4096 + (size_t)(i >> 1) * 128 + lane * 2 + (i & 1)] = bits;
        }
        float contrib = Bj * (logf(Bj + EPSV) - lC + en);
        contrib = wave_sum64(contrib);
        if (lane == 0) {
            lse[row] = m + logf(ssum);
            rws[row] = -contrib;
        }
    }
}

// ------- VI: thread-owns-row, q streamed to global workspace -------
__global__ __launch_bounds__(512) void vi_kernel(
    const float* __restrict__ theta, const float* __restrict__ lse,
    const float* __restrict__ rws, float* __restrict__ q_ws)
{
    __shared__ float q_lds[KDIM * 68];
    __shared__ __align__(16) float v_lds[68];
    const int n = blockIdx.x, tid = threadIdx.x;
    const float* Xn = theta + (size_t)n * NP + 4096;

    const float l0  = lse[(size_t)n * 1024 + tid];
    const float l1  = lse[(size_t)n * 1024 + 512 + tid];
    const float rr0 = rws[(size_t)n * 1024 + tid];
    const float rr1 = rws[(size_t)n * 1024 + 512 + tid];

    float4 er0[16], er1[16];
    {
        const float* X0 = Xn + (size_t)tid * 64;
        const float* X1 = Xn + (size_t)(512 + tid) * 64;
#pragma unroll
        for (int j = 0; j < 16; ++j) {
            float4 x = *(const float4*)(X0 + j * 4);
            er0[j] = make_float4(__expf(x.x - l0), __expf(x.y - l0),
                                 __expf(x.z - l0), __expf(x.w - l0));
            float4 y = *(const float4*)(X1 + j * 4);
            er1[j] = make_float4(__expf(y.x - l1), __expf(y.y - l1),
                                 __expf(y.z - l1), __expf(y.w - l1));
        }
    }

    float qr0 = rr0, qr1 = rr1;
    float* qw = q_ws + (size_t)n * HDIM * 1024;
    const int kq0 = tid >> 6, iq = tid & 63;
    qw[tid] = qr0;
    qw[512 + tid] = qr1;
    q_lds[kq0 * 68 + iq] = qr0;
    q_lds[(8 + kq0) * 68 + iq] = qr1;
    __syncthreads();

#pragma unroll 1
    for (int h = 1; h < HDIM; ++h) {
        if (tid < 64) {
            float m = -1e30f;
#pragma unroll
            for (int k = 0; k < KDIM; ++k) m = fmaxf(m, q_lds[k * 68 + tid]);
            float s = 0.f;
#pragma unroll
            for (int k = 0; k < KDIM; ++k) s += __expf(q_lds[k * 68 + tid] - m);
            v_lds[tid] = m + __logf(s);
        }
        bar_lds();
        float a0x = 0.f, a0y = 0.f, a0z = 0.f, a0w = 0.f;
        float a1x = 0.f, a1y = 0.f, a1z = 0.f, a1w = 0.f;
#pragma unroll
        for (int jq = 0; jq < 16; ++jq) {
            const float4 v4 = *(const float4*)&v_lds[jq * 4];
            a0x += er0[jq].x * v4.x; a0y += er0[jq].y * v4.y;
            a0z += er0[jq].z * v4.z; a0w += er0[jq].w * v4.w;
            a1x += er1[jq].x * v4.x; a1y += er1[jq].y * v4.y;
            a1z += er1[jq].z * v4.z; a1w += er1[jq].w * v4.w;
        }
        qr0 = rr0 + ((a0x + a0y) + (a0z + a0w));
        qr1 = rr1 + ((a1x + a1y) + (a1z + a1w));
        qw[(size_t)h * 1024 + tid] = qr0;
        qw[(size_t)h * 1024 + 512 + tid] = qr1;
        q_lds[kq0 * 68 + iq] = qr0;
        q_lds[(8 + kq0) * 68 + iq] = qr1;
        bar_lds();
    }
}

// ======= TIER-1 fused belief+policy: 4 waves, 1 barrier/step =======
// belief as round-15 belief4 (bf16 B, shfl-b matvec, pipelined ecz).
// policy rides post-barrier: thread owns rows (hA=tid>>4,k) and (hA+16,k),
// q-rows in 128 VGPR; b_t broadcast from b2_s; pi(t-1) emitted next step.
#define BSP(T_, U_) do {                                                       \
    const int cur_ = (T_) & 1, nxt_ = cur_ ^ 1;                                \
    if (wave == 3) out_b[((size_t)(T_) * NDIM + n) * SDIM + lane] = bval;      \
    if (wave == 1) b2_s[cur_][lane] = bval;                                    \
    {   /* matvec via shfl-distributed b */                                    \
        float a0_ = 0.f, a1_ = 0.f, a2_ = 0.f, a3_ = 0.f;                      \
        _Pragma("unroll")                                                      \
        for (int j_ = 0; j_ < 4; ++j_) {                                       \
            a0_ += er[4 * j_ + 0] * __shfl(bval, rbase + 4 * j_ + 0, 64);      \
            a1_ += er[4 * j_ + 1] * __shfl(bval, rbase + 4 * j_ + 1, 64);      \
            a2_ += er[4 * j_ + 2] * __shfl(bval, rbase + 4 * j_ + 2, 64);      \
            a3_ += er[4 * j_ + 3] * __shfl(bval, rbase + 4 * j_ + 3, 64);      \
        }                                                                      \
        part_s[cur_][wave][lane] = (a0_ + a1_) + (a2_ + a3_);                  \
    }                                                                          \
    if ((T_) + 1 < TDIM) {               /* z2 partial for t+1 */              \
        const float* om_ = &o_s[((T_) + 1) * ODIM + ob];                       \
        float zz_ = 0.f;                                                       \
        _Pragma("unroll")                                                      \
        for (int j_ = 0; j_ < 8; ++j_) {                                       \
            float z_ = (om_[j_] - mean_r[j_]) * istd_r[j_];                    \
            zz_ += z_ * z_;                                                    \
        }                                                                      \
        z2p_s[nxt_][wave][lane] = zz_;                                         \
    }                                                                          \
    _Pragma("unroll")                     /* unpack next-step B rows */        \
    for (int m_ = 0; m_ < 8; ++m_) {                                           \
        er[2 * m_]     = __uint_as_float(U_[m_] << 16);                        \
        er[2 * m_ + 1] = __uint_as_float(U_[m_] & 0xffff0000u);                \
    }                                                                          \
    {   /* prefetch B(a_{T+3}) */                                              \
        const int tl_ = ((T_) + 3 < TDIM) ? (T_) + 3 : TDIM - 1;               \
        const uint* up_ = bnn32 + (size_t)a_s[tl_] * 2048 + (rbase >> 1) * 64 + lane; \
        _Pragma("unroll")                                                      \
        for (int m_ = 0; m_ < 8; ++m_) U_[m_] = up_[m_ * 64];                  \
    }                                                                          \
    bar_lds();                           /* the ONE barrier */                 \
    {   /* belief update (x4 redundant) + pipelined ecz(t+1) */                \
        float sv_ = part_s[cur_][0][lane] + part_s[cur_][1][lane]              \
                  + part_s[cur_][2][lane] + part_s[cur_][3][lane];             \
        float u_ = (sv_ + EPSV) * ecz_cur;                                     \
        float S_ = wave_sum64(u_);                                             \
        if (wave == 0 && lane == 0)                                            \
            out_lp[(size_t)(T_) * NDIM + n] = cm_cur + __logf(S_);             \
        bval = u_ / S_;                                                        \
        float z2n_ = z2p_s[nxt_][0][lane] + z2p_s[nxt_][1][lane]               \
                   + z2p_s[nxt_][2][lane] + z2p_s[nxt_][3][lane];              \
        float cn_ = c0_r - 0.5f * z2n_;                                        \
        cm_cur = wave_max64(cn_);                                              \
        ecz_cur = __expf(cn_ - cm_cur);                                        \
    }                                                                          \
    {   /* policy(T) from b2_s[cur_] (written pre-barrier) */                  \
        float aAx_ = 0.f, aAy_ = 0.f, aAz_ = 0.f, aAw_ = 0.f;                  \
        float aBx_ = 0.f, aBy_ = 0.f, aBz_ = 0.f, aBw_ = 0.f;                  \
        _Pragma("unroll")                                                      \
        for (int jq_ = 0; jq_ < 16; ++jq_) {                                   \
            const float4 b4_ = *(const float4*)&b2_s[cur_][jq_ * 4];           \
            aAx_ += qA[jq_].x * b4_.x; aAy_ += qA[jq_].y * b4_.y;              \
            aAz_ += qA[jq_].z * b4_.z; aAw_ += qA[jq_].w * b4_.w;              \
            aBx_ += qB[jq_].x * b4_.x; aBy_ += qB[jq_].y * b4_.y;              \
            aBz_ += qB[jq_].z * b4_.z; aBw_ += qB[jq_].w * b4_.w;              \
        }                                                                      \
        float aA_ = (aAx_ + aAy_) + (aAz_ + aAw_);                             \
        float aB_ = (aBx_ + aBy_) + (aBz_ + aBw_);                             \
        float mA_ = aA_, mB_ = aB_;                                            \
        mA_ = fmaxf(mA_, __shfl_xor(mA_, 1, 64));                              \
        mB_ = fmaxf(mB_, __shfl_xor(mB_, 1, 64));                              \
        mA_ = fmaxf(mA_, __shfl_xor(mA_, 2, 64));                              \
        mB_ = fmaxf(mB_, __shfl_xor(mB_, 2, 64));                              \
        mA_ = fmaxf(mA_, __shfl_xor(mA_, 4, 64));                              \
        mB_ = fmaxf(mB_, __shfl_xor(mB_, 4, 64));                              \
        mA_ = fmaxf(mA_, __shfl_xor(mA_, 8, 64));                              \
        mB_ = fmaxf(mB_, __shfl_xor(mB_, 8, 64));                              \
        float eA_ = __expf(aA_ - mA_), eB_ = __expf(aB_ - mB_);                \
        float SA_ = eA_, SB_ = eB_;                                            \
        SA_ += __shfl_xor(SA_, 1, 64);  SB_ += __shfl_xor(SB_, 1, 64);         \
        SA_ += __shfl_xor(SA_, 2, 64);  SB_ += __shfl_xor(SB_, 2, 64);         \
        SA_ += __shfl_xor(SA_, 4, 64);  SB_ += __shfl_xor(SB_, 4, 64);         \
        SA_ += __shfl_xor(SA_, 8, 64);  SB_ += __shfl_xor(SB_, 8, 64);         \
        float val_ = pdfA * eA_ / SA_ + pdfB * eB_ / SB_;                      \
        val_ += __shfl_xor(val_, 16, 64);                                      \
        val_ += __shfl_xor(val_, 32, 64);                                      \
        if (lane < 16) p2_s[cur_][wave][lane] = val_;                          \
        if ((T_) > 0 && wave == 3 && lane < 16) {                              \
            float s4_ = p2_s[nxt_][0][lane] + p2_s[nxt_][1][lane]              \
                      + p2_s[nxt_][2][lane] + p2_s[nxt_][3][lane];             \
            out_pi[((size_t)((T_) - 1) * NDIM + n) * KDIM + lane] = s4_;       \
        }                                                                      \
    }                                                                          \
} while (0)

__global__ __launch_bounds__(256, 2) void bp_kernel(
    const float* __restrict__ o, const int* __restrict__ a,
    const float* __restrict__ theta, const __hip_bfloat16* __restrict__ bn,
    const float* __restrict__ invstd, const float* __restrict__ c0g,
    const float* __restrict__ Dws, const float* __restrict__ pdfg,
    const float* __restrict__ q_ws,
    float* __restrict__ out_pi, float* __restrict__ out_b,
    float* __restrict__ out_lp)
{
    __shared__ float o_s[TDIM * ODIM];       // 25.6 KB
    __shared__ int   a_s[TDIM];
    __shared__ float mean_s[SDIM * 33];
    __shared__ float istd_s[SDIM * 33];
    __shared__ float c0_sh[SDIM];
    __shared__ float part_s[2][4][68];
    __shared__ float z2p_s[2][4][SDIM];
    __shared__ __align__(16) float b2_s[2][SDIM];
    __shared__ float p2_s[2][4][17];

    const int n = blockIdx.x, tid = threadIdx.x;
    const int wave = tid >> 6, lane = tid & 63;
    const int rbase = wave * 16, ob = wave * 8;
    const float* thn = theta + (size_t)n * NP;
    const uint* bnn32 = (const uint*)(bn + (size_t)n * KDIM * SDIM * SDIM);

    for (int idx = tid; idx < TDIM * ODIM; idx += 256)
        o_s[idx] = o[((size_t)(idx >> 5) * NDIM + n) * ODIM + (idx & 31)];
    if (tid < TDIM) a_s[tid] = a[tid * NDIM + n];
    for (int idx = tid; idx < SDIM * ODIM; idx += 256) {
        int s = idx >> 5, oo = idx & 31;
        mean_s[s * 33 + oo] = thn[idx];
        istd_s[s * 33 + oo] = invstd[(size_t)n * SDIM * ODIM + idx];
    }
    if (tid < SDIM) c0_sh[tid] = c0g[n * SDIM + tid];

    // --- policy state: q-rows in registers ---
    const int hA = tid >> 4, kA = tid & 15, hB = hA + 16;
    const float* qnp = q_ws + (size_t)n * HDIM * 1024;
    float4 qA[16], qB[16];
#pragma unroll
    for (int jq = 0; jq < 16; ++jq)
        qA[jq] = *(const float4*)&qnp[(size_t)hA * 1024 + kA * 64 + jq * 4];
    if (hB < HDIM) {
#pragma unroll
        for (int jq = 0; jq < 16; ++jq)
            qB[jq] = *(const float4*)&qnp[(size_t)hB * 1024 + kA * 64 + jq * 4];
    } else {
#pragma unroll
        for (int jq = 0; jq < 16; ++jq) qB[jq] = make_float4(0.f, 0.f, 0.f, 0.f);
    }
    const float pdfA = pdfg[n * HDIM + hA];
    const float pdfB = (hB < HDIM) ? pdfg[n * HDIM + hB] : 0.f;
    __syncthreads();

    const float c0_r = c0_sh[lane];
    float bval = Dws[n * SDIM + lane];
    float mean_r[8], istd_r[8];
#pragma unroll
    for (int j = 0; j < 8; ++j) {
        mean_r[j] = mean_s[lane * 33 + ob + j];
        istd_r[j] = istd_s[lane * 33 + ob + j];
    }

    float er[16];
    uint u0[8], u1[8];
    {   // prologue: er <- B(a_0); u0 <- B(a_1); u1 <- B(a_2)
        const uint* p0 = bnn32 + (size_t)a_s[0] * 2048 + (rbase >> 1) * 64 + lane;
#pragma unroll
        for (int m = 0; m < 8; ++m) u0[m] = p0[m * 64];
#pragma unroll
        for (int m = 0; m < 8; ++m) {
            er[2 * m]     = __uint_as_float(u0[m] << 16);
            er[2 * m + 1] = __uint_as_float(u0[m] & 0xffff0000u);
        }
        const uint* p1 = bnn32 + (size_t)a_s[1] * 2048 + (rbase >> 1) * 64 + lane;
#pragma unroll
        for (int m = 0; m < 8; ++m) u0[m] = p1[m * 64];
        const uint* p2 = bnn32 + (size_t)a_s[2] * 2048 + (rbase >> 1) * 64 + lane;
#pragma unroll
        for (int m = 0; m < 8; ++m) u1[m] = p2[m * 64];
    }
    {   // z2p for t=0
        const float* om = &o_s[ob];
        float zz = 0.f;
#pragma unroll
        for (int j = 0; j < 8; ++j) {
            float z = (om[j] - mean_r[j]) * istd_r[j];
            zz += z * z;
        }
        z2p_s[0][wave][lane] = zz;
    }
    __syncthreads();
    float ecz_cur, cm_cur;
    {   // ecz(0)
        float z2 = z2p_s[0][0][lane] + z2p_s[0][1][lane]
                 + z2p_s[0][2][lane] + z2p_s[0][3][lane];
        float c = c0_r - 0.5f * z2;
        cm_cur = wave_max64(c);
        ecz_cur = __expf(c - cm_cur);
    }

#pragma unroll 1
    for (int t = 0; t < TDIM; t += 2) {
        BSP(t, u0);
        BSP(t + 1, u1);
    }
    __syncthreads();
    if (wave == 3 && lane < 16) {    // emit pi(TDIM-1), buffer (TDIM-1)&1 = 1
        float s4 = p2_s[1][0][lane] + p2_s[1][1][lane]
                 + p2_s[1][2][lane] + p2_s[1][3][lane];
        out_pi[((size_t)(TDIM - 1) * NDIM + n) * KDIM + lane] = s4;
    }
}

// ===================== TIER-3 fallback (f32, no extra ws) =====================
#define Z2PART(TT_, BUF_) do {                                                 \
    const int ob_ = (wave - 1) * 8;                                            \
    const float* om_ = &o_s[(TT_) * ODIM + ob_];                               \
    float zz_ = 0.f;                                                           \
    _Pragma("unroll")                                                          \
    for (int j_ = 0; j_ < 8; ++j_) {                                           \
        float z_ = (om_[j_] - mean_s[lane * 33 + ob_ + j_])                    \
                 * istd_s[lane * 33 + ob_ + j_];                               \
        zz_ += z_ * z_;                                                        \
    }                                                                          \
    z2p_s[BUF_][wave - 1][lane] = zz_;                                         \
} while (0)

#define BSTEP(T_, RAW_) do {                                                   \
    const int cur_ = (T_) & 1, nxt_ = cur_ ^ 1;                                \
    if (wave >= 1) {                                                           \
        float acc_ = 0.f;                                                      \
        _Pragma("unroll")                                                      \
        for (int ii = 0; ii < 10; ++ii)                                        \
            if (ii < nrow) acc_ += er[ii] * b_s[cur_][rbase + ii];             \
        part_s[wave - 1][lane] = acc_;                                         \
        if (wave == 6) out_b[((size_t)(T_) * NDIM + n) * SDIM + lane] = b_s[cur_][lane]; \
    }                                                                          \
    bar_lds();                                                                 \
    if (wave == 0) {                                                           \
        float sv_ = part_s[0][lane] + part_s[1][lane] + part_s[2][lane]        \
                  + part_s[3][lane] + part_s[4][lane] + part_s[5][lane]        \
                  + part_s[6][lane];                                           \
        float z2_ = z2p_s[cur_][0][lane] + z2p_s[cur_][1][lane]                \
                  + z2p_s[cur_][2][lane] + z2p_s[cur_][3][lane];               \
        float joint_ = __logf(sv_ + EPSV) + c0_s[lane] - 0.5f * z2_;           \
        float m_ = wave_max64(joint_);                                         \
        float e_ = __expf(joint_ - m_);                                        \
        float ss_ = wave_sum64(e_);                                            \
        b_s[nxt_][lane] = e_ / ss_;                                            \
        if (lane == 0) out_lp[(size_t)(T_) * NDIM + n] = m_ + __logf(ss_);     \
    } else {                                                                   \
        if ((T_) + 1 < TDIM) {                                                 \
            const int an_ = a_s[(T_) + 1];                                     \
            const float* ln_ = lseA + an_ * SDIM;                              \
            _Pragma("unroll")                                                  \
            for (int ii = 0; ii < 10; ++ii)                                    \
                if (ii < nrow) er[ii] = __expf(RAW_[ii] - ln_[rbase + ii]);    \
            if (wave <= 4) Z2PART((T_) + 1, nxt_);                             \
        }                                                                      \
        const int tl_ = ((T_) + 3 < TDIM) ? (T_) + 3 : TDIM - 1;               \
        const int a3_ = a_s[tl_];                                              \
        const float* X3_ = Xn + (size_t)a3_ * SDIM * SDIM;                     \
        _Pragma("unroll")                                                      \
        for (int ii = 0; ii < 10; ++ii)                                        \
            if (ii < nrow) RAW_[ii] = X3_[(size_t)(rbase + ii) * SDIM + lane]; \
    }                                                                          \
    bar_lds();                                                                 \
} while (0)

__global__ __launch_bounds__(512) void belief_kernel(
    const float* __restrict__ o, const int* __restrict__ a,
    const float* __restrict__ theta, const float* __restrict__ lse,
    const float* __restrict__ invstd, const float* __restrict__ c0g,
    const float* __restrict__ Dws,
    float* __restrict__ out_b, float* __restrict__ out_lp)
{
    __shared__ float o_s[TDIM * ODIM];
    __shared__ int   a_s[TDIM];
    __shared__ float mean_s[SDIM * 33];
    __shared__ float istd_s[SDIM * 33];
    __shared__ float lseA[KDIM * SDIM];
    __shared__ float c0_s[SDIM];
    __shared__ float b_s[2][SDIM];
    __shared__ float part_s[7][68];
    __shared__ float z2p_s[2][4][SDIM];

    const int n = blockIdx.x, tid = threadIdx.x;
    const int wave = tid >> 6, lane = tid & 63;
    const float* thn = theta + (size_t)n * NP;
    const float* Xn  = thn + 4096;

    for (int idx = tid; idx < TDIM * ODIM; idx += 512)
        o_s[idx] = o[((size_t)(idx >> 5) * NDIM + n) * ODIM + (idx & 31)];
    if (tid < TDIM) a_s[tid] = a[tid * NDIM + n];
    for (int idx = tid; idx < SDIM * ODIM; idx += 512) {
        int s = idx >> 5, oo = idx & 31;
        mean_s[s * 33 + oo] = thn[idx];
        istd_s[s * 33 + oo] = invstd[(size_t)n * SDIM * ODIM + idx];
    }
    for (int idx = tid; idx < KDIM * SDIM; idx += 512)
        lseA[idx] = lse[(size_t)n * KDIM * SDIM + idx];
    if (tid < SDIM) { c0_s[tid] = c0g[n * SDIM + tid]; b_s[0][tid] = Dws[n * SDIM + tid]; }
    __syncthreads();

    const int rbase = (wave >= 1) ? (wave - 1) * 10 : 0;
    const int nrow  = (wave >= 1) ? ((SDIM - rbase) < 10 ? (SDIM - rbase) : 10) : 0;

    float er[10], raw0[10], raw1[10];
    if (wave >= 1) {
        const int a0 = a_s[0];
        const float* X0 = Xn + (size_t)a0 * SDIM * SDIM;
        const float* l0 = lseA + a0 * SDIM;
#pragma unroll
        for (int ii = 0; ii < 10; ++ii)
            if (ii < nrow) er[ii] = __expf(X0[(size_t)(rbase + ii) * SDIM + lane] - l0[rbase + ii]);
        const int a1 = a_s[1];
        const float* X1 = Xn + (size_t)a1 * SDIM * SDIM;
#pragma unroll
        for (int ii = 0; ii < 10; ++ii)
            if (ii < nrow) raw0[ii] = X1[(size_t)(rbase + ii) * SDIM + lane];
        const int a2 = a_s[2];
        const float* X2 = Xn + (size_t)a2 * SDIM * SDIM;
#pragma unroll
        for (int ii = 0; ii < 10; ++ii)
            if (ii < nrow) raw1[ii] = X2[(size_t)(rbase + ii) * SDIM + lane];
        if (wave <= 4) Z2PART(0, 0);
    }
    __syncthreads();

#pragma unroll 1
    for (int t = 0; t < TDIM; t += 2) {
        BSTEP(t, raw0);
        BSTEP(t + 1, raw1);
    }
}

__global__ __launch_bounds__(512) void vi_policy_kernel(
    const float* __restrict__ theta, const float* __restrict__ lse,
    const float* __restrict__ rws, const float* __restrict__ pdfg,
    const float* __restrict__ out_b_g, float* __restrict__ out_pi)
{
    __shared__ __align__(16) float q_s[HDIM * KDIM * 68];
    __shared__ float r_s[KDIM * SDIM];
    __shared__ float lse_s[KDIM * SDIM];
    __shared__ __align__(16) float v_s[SDIM];
    __shared__ __align__(16) float b_lds[64 * 68];
    __shared__ float pdf_s[32];

    const int n = blockIdx.x, tid = threadIdx.x;
    const int wave = tid >> 6, lane = tid & 63;
    const int sub = lane & 15, rq = lane >> 4;
    const float* Xn = theta + (size_t)n * NP + 4096;

    for (int idx = tid; idx < KDIM * SDIM; idx += 512) {
        r_s[idx]   = rws[(size_t)n * KDIM * SDIM + idx];
        lse_s[idx] = lse[(size_t)n * KDIM * SDIM + idx];
    }
    if (tid < HDIM) pdf_s[tid] = pdfg[n * HDIM + tid];
    __syncthreads();

    for (int idx = tid; idx < KDIM * SDIM; idx += 512)
        q_s[(idx >> 6) * 68 + (idx & 63)] = r_s[idx];

    float4 breg[32];
#pragma unroll
    for (int it = 0; it < 32; ++it) {
        const int row = it * 32 + wave * 4 + rq;
        const float* xr = Xn + (size_t)row * SDIM + sub * 4;
        const float l = lse_s[row];
        breg[it] = make_float4(__expf(xr[0] - l), __expf(xr[1] - l),
                               __expf(xr[2] - l), __expf(xr[3] - l));
    }
    bar_lds();

#pragma unroll 1
    for (int h = 1; h < HDIM; ++h) {
        if (tid < SDIM) {
            const int base = (h - 1) * KDIM;
            float m = -1e30f;
#pragma unroll
            for (int k = 0; k < KDIM; ++k) m = fmaxf(m, q_s[(base + k) * 68 + tid]);
            float ssum = 0.f;
#pragma unroll
            for (int k = 0; k < KDIM; ++k) ssum += __expf(q_s[(base + k) * 68 + tid] - m);
            v_s[tid] = m + __logf(ssum);
        }
        bar_lds();
        const float4 v4 = *(const float4*)&v_s[sub * 4];
#pragma unroll
        for (int it = 0; it < 32; ++it) {
            const int row = it * 32 + wave * 4 + rq;
            float acc = breg[it].x * v4.x + breg[it].y * v4.y
                      + breg[it].z * v4.z + breg[it].w * v4.w;
            acc += __shfl_xor(acc, 1, 64);
            acc += __shfl_xor(acc, 2, 64);
            acc += __shfl_xor(acc, 4, 64);
            acc += __shfl_xor(acc, 8, 64);
            if (sub == 0)
                q_s[(h * KDIM + (row >> 6)) * 68 + (row & 63)] = r_s[row] + acc;
        }
        bar_lds();
    }

    const int tc = tid >> 4, kk = tid & 15;
#pragma unroll 1
    for (int t0 = 0; t0 < TDIM; t0 += 64) {
        const int nt = (TDIM - t0) < 64 ? (TDIM - t0) : 64;
        for (int idx = tid; idx < nt * 16; idx += 512) {
            const int row = idx >> 4, jq = idx & 15;
            *(float4*)&b_lds[row * 68 + jq * 4] =
                *(const float4*)&out_b_g[(((size_t)(t0 + row)) * NDIM + n) * SDIM + jq * 4];
        }
        bar_lds();
        const bool vA = tc < nt, vB = (tc + 32) < nt;
        float4 bqA[16], bqB[16];
        if (vA) {
#pragma unroll
            for (int jq = 0; jq < 16; ++jq)
                bqA[jq] = *(const float4*)&b_lds[tc * 68 + jq * 4];
        }
        if (vB) {
#pragma unroll
            for (int jq = 0; jq < 16; ++jq)
                bqB[jq] = *(const float4*)&b_lds[(tc + 32) * 68 + jq * 4];
        }
        float pikA = 0.f, pikB = 0.f;
#pragma unroll 1
        for (int h = 0; h < HDIM; ++h) {
            const float* qr = &q_s[(h * KDIM + kk) * 68];
            float aA = 0.f, aB = 0.f;
#pragma unroll
            for (int jq = 0; jq < 16; ++jq) {
                const float4 qv = *(const float4*)&qr[jq * 4];
                if (vA) aA += qv.x * bqA[jq].x + qv.y * bqA[jq].y
                            + qv.z * bqA[jq].z + qv.w * bqA[jq].w;
                if (vB) aB += qv.x * bqB[jq].x + qv.y * bqB[jq].y
                            + qv.z * bqB[jq].z + qv.w * bqB[jq].w;
            }
            float mA = aA, mB = aB;
            mA = fmaxf(mA, __shfl_xor(mA, 1, 64));
            mA = fmaxf(mA, __shfl_xor(mA, 2, 64));
            mA = fmaxf(mA, __shfl_xor(mA, 4, 64));
            mA = fmaxf(mA, __shfl_xor(mA, 8, 64));
            mB = fmaxf(mB, __shfl_xor(mB, 1, 64));
            mB = fmaxf(mB, __shfl_xor(mB, 2, 64));
            mB = fmaxf(mB, __shfl_xor(mB, 4, 64));
            mB = fmaxf(mB, __shfl_xor(mB, 8, 64));
            float eA = __expf(aA - mA), eB = __expf(aB - mB);
            float SA = eA, SB = eB;
            SA += __shfl_xor(SA, 1, 64);
            SA += __shfl_xor(SA, 2, 64);
            SA += __shfl_xor(SA, 4, 64);
            SA += __shfl_xor(SA, 8, 64);
            SB += __shfl_xor(SB, 1, 64);
            SB += __shfl_xor(SB, 2, 64);
            SB += __shfl_xor(SB, 4, 64);
            SB += __shfl_xor(SB, 8, 64);
            const float ph = pdf_s[h];
            pikA += ph * eA / SA;
            pikB += ph * eB / SB;
        }
        if (vA) out_pi[(((size_t)(t0 + tc)) * NDIM + n) * KDIM + kk] = pikA;
        if (vB) out_pi[(((size_t)(t0 + 32 + tc)) * NDIM + n) * KDIM + kk] = pikB;
        bar_lds();
    }
}

extern "C" void kernel_launch(void* const* d_in, const int* in_sizes, int n_in,
                              void* d_out, int out_size, void* d_ws, size_t ws_size,
                              hipStream_t stream) {
    (void)in_sizes; (void)n_in; (void)out_size;
    const float* o     = (const float*)d_in[0];
    const int*   a     = (const int*)d_in[1];
    const float* theta = (const float*)d_in[2];
    float* out = (float*)d_out;
    float* ws  = (float*)d_ws;

    float* lse    = ws;                                   // N*K*S
    float* rws    = lse    + (size_t)NDIM * KDIM * SDIM;  // N*K*S
    float* invstd = rws    + (size_t)NDIM * KDIM * SDIM;  // N*S*O
    float* c0     = invstd + (size_t)NDIM * SDIM * ODIM;  // N*S
    float* ent    = c0     + (size_t)NDIM * SDIM;         // N*S
    float* logC   = ent    + (size_t)NDIM * SDIM;         // N*S
    float* Dws    = logC   + (size_t)NDIM * SDIM;         // N*S
    float* pdfws  = Dws    + (size_t)NDIM * SDIM;         // N*H
    float* q_ws   = pdfws  + (size_t)NDIM * HDIM;         // N*H*K*S f32 (63 MB)
    __hip_bfloat16* bn = (__hip_bfloat16*)(q_ws + (size_t)NDIM * HDIM * KDIM * SDIM);

    const size_t f_base = (size_t)NDIM * KDIM * SDIM * 2
                        + (size_t)NDIM * SDIM * ODIM
                        + (size_t)NDIM * SDIM * 4
                        + (size_t)NDIM * HDIM;
    const size_t f_q  = (size_t)NDIM * HDIM * KDIM * SDIM;
    const size_t need1 = (f_base + f_q) * 4
                       + (size_t)NDIM * KDIM * SDIM * SDIM * 2;   // ~139 MB

    float* out_pi = out;
    float* out_b  = out + (size_t)TDIM * NDIM * KDIM;
    float* out_lp = out + (size_t)TDIM * NDIM * KDIM + (size_t)TDIM * NDIM * SDIM;

    transform_kernel<<<NDIM, 256, 0, stream>>>(theta, invstd, c0, ent, logC, Dws, pdfws);

    if (ws_size >= need1) {
        row_stats_kernel<<<8192, 256, 0, stream>>>(theta, logC, ent, lse, rws, bn);
        vi_kernel<<<NDIM, 512, 0, stream>>>(theta, lse, rws, q_ws);
        bp_kernel<<<NDIM, 256, 0, stream>>>(
            o, a, theta, bn, invstd, c0, Dws, pdfws, q_ws, out_pi, out_b, out_lp);
    } else {
        row_stats_kernel<<<8192, 256, 0, stream>>>(
            theta, logC, ent, lse, rws, (__hip_bfloat16*)nullptr);
        belief_kernel<<<NDIM, 512, 0, stream>>>(
            o, a, theta, lse, invstd, c0, Dws, out_b, out_lp);
        vi_policy_kernel<<<NDIM, 512, 0, stream>>>(theta, lse, rws, pdfws, out_b, out_pi);
    }
}